// Round 5
// baseline (537.235 us; speedup 1.0000x reference)
//
#include <hip/hip_runtime.h>
#include <cstdint>
#include <cstddef>

#define NLAB 128
#define TT   512
#define BB   512
#define MB   16        // batches per block
#define PAD_ 0
#define BOS_ 1
#define EOS_ 2

typedef float f32x4 __attribute__((ext_vector_type(4)));
typedef short s16x8 __attribute__((ext_vector_type(8)));

// ---- mask dtype hedge: bool(1B) vs int32(4B) -------------------------------
__device__ __forceinline__ bool mask_is_i32(const unsigned char* m8) {
    return m8[1] == 0;   // mask[0][1] always true; int32 high byte => 0
}
__device__ __forceinline__ bool mask_at(const unsigned char* m8, int idx, bool isi) {
    if (isi) return ((const int*)m8)[idx] != 0;
    return m8[idx] != 0;
}

__device__ __forceinline__ unsigned short f2bf(float f) {
    union { float f; unsigned u; } v; v.f = f;
    unsigned r = v.u + 0x7FFFu + ((v.u >> 16) & 1u);   // RNE; inputs finite>=0
    return (unsigned short)(r >> 16);
}

// B-fragment of E=exp(tr) for mfma_f32_16x16x32_bf16:
// lane holds B[k][n], n = lane&15 (passed as n), k = kbase + jj (8 consecutive)
__device__ __forceinline__ s16x8 ebfrag(const float* __restrict__ tr, int kbase, int n) {
    s16x8 r;
    #pragma unroll
    for (int jj = 0; jj < 8; ++jj)
        r[jj] = (short)f2bf(__expf(tr[(kbase + jj) * NLAB + n]));
    return r;
}

// ---- forward + gold fused: 16 batches / block, 512 thr (8 waves) -----------
__global__ __launch_bounds__(512, 2) void crf_forward(
        const float* __restrict__ feats,
        const int*   __restrict__ tags,
        const unsigned char* __restrict__ m8,
        const float* __restrict__ tr,
        float* __restrict__ gold_out,
        float* __restrict__ logZ_out) {
    const int tid  = threadIdx.x;
    const int blk  = blockIdx.x;
    const int w    = tid >> 6;       // wave 0..7  (N-tile)
    const int l    = tid & 63;
    const int quad = l >> 4;         // 0..3
    const int col  = l & 15;
    const int j    = w * 16 + col;   // label column this lane owns (C-layout)
    const bool isi = mask_is_i32(m8);

    __shared__ unsigned short P16[2][2048];   // 16x128 bf16, A-frag layout, dbuf
    __shared__ float u3_sh[2][MB];
    __shared__ float gsh[MB];
    __shared__ int   csh[MB];
    __shared__ int   len_sh[MB];
    __shared__ float red_m[8][MB];
    __shared__ float red_s[8][MB];
    __shared__ float mfin[MB];

    // ---- gold + length: 32 threads per batch ----
    {
        const int bl = tid >> 5, sub = tid & 31;
        const int Bg = blk * MB + bl;
        const size_t fb = (size_t)Bg * TT * NLAB;
        float gp = 0.f; int cnt = 0;
        for (int tt = sub; tt < TT; tt += 32) {
            const int idx = Bg * TT + tt;
            const bool mm = mask_at(m8, idx, isi);
            cnt += mm ? 1 : 0;
            const int tg = tags[idx];
            if (tt == 0) gp += feats[fb + tg] + tr[BOS_ * NLAB + tg];
            else if (mm) gp += feats[fb + (size_t)tt * NLAB + tg]
                             + tr[tags[idx - 1] * NLAB + tg];
        }
        #pragma unroll
        for (int off = 16; off > 0; off >>= 1) {
            gp  += __shfl_xor(gp,  off, 64);
            cnt += __shfl_xor(cnt, off, 64);
        }
        if (sub == 0) { gsh[bl] = gp; csh[bl] = cnt; }
    }
    __syncthreads();
    if (tid < MB) {
        const int len = csh[tid];
        len_sh[tid] = len;
        const int Bg = blk * MB + tid;
        const int last = tags[Bg * TT + (len - 1)];
        gold_out[Bg] = gsh[tid] + tr[last * NLAB + EOS_];
    }

    // ---- loop-invariant E B-fragments: 4 x s16x8 = 16 VGPRs / lane ----
    const s16x8 Bf0 = ebfrag(tr, 0 * 32 + quad * 8, j);
    const s16x8 Bf1 = ebfrag(tr, 1 * 32 + quad * 8, j);
    const s16x8 Bf2 = ebfrag(tr, 2 * 32 + quad * 8, j);
    const s16x8 Bf3 = ebfrag(tr, 3 * 32 + quad * 8, j);

    const float trB = tr[BOS_ * NLAB + j];
    const float trE = tr[j * NLAB + EOS_];

    // lane owns (b_i = quad*4+i, j) in C-layout; fp32 state in registers
    const int fb0 = (blk * MB + quad * 4 + 0) * (TT * NLAB) + j;
    const int fb1 = (blk * MB + quad * 4 + 1) * (TT * NLAB) + j;
    const int fb2 = (blk * MB + quad * 4 + 2) * (TT * NLAB) + j;
    const int fb3 = (blk * MB + quad * 4 + 3) * (TT * NLAB) + j;

    float u0 = trB + feats[fb0];
    float u1 = trB + feats[fb1];
    float u2 = trB + feats[fb2];
    float u3r = trB + feats[fb3];
    if (w == 0 && col == 3) {           // label 3 always live: normalizer source
        u3_sh[0][quad * 4 + 0] = u0;
        u3_sh[0][quad * 4 + 1] = u1;
        u3_sh[0][quad * 4 + 2] = u2;
        u3_sh[0][quad * 4 + 3] = u3r;
    }
    __syncthreads();   // len_sh + u3_sh[0] ready

    const int4 L4 = ((const int4*)len_sh)[quad];
    const int len0 = L4.x, len1 = L4.y, len2 = L4.z, len3 = L4.w;
    int maxlen = 0;
    #pragma unroll
    for (int b = 0; b < MB; ++b) maxlen = max(maxlen, len_sh[b]);

    float4 n4 = ((const float4*)u3_sh[0])[quad];
    float C0 = 0.f, C1 = 0.f, C2 = 0.f, C3 = 0.f;

    // P LDS addresses (A-frag layout): addr16(b,j) = ((j>>3)*16 + b)*8 + (j&7)
    const int wa0 = ((j >> 3) * 16 + quad * 4 + 0) * 8 + (j & 7);
    const int wa1 = wa0 + 8, wa2 = wa0 + 16, wa3 = wa0 + 24;
    // A-frag read chunks: lane reads A[m=col][k = kt*32 + quad*8 .. +7]
    const int ca0 = ((0 * 4 + quad) * 16 + col);
    const int ca1 = ((1 * 4 + quad) * 16 + col);
    const int ca2 = ((2 * 4 + quad) * 16 + col);
    const int ca3 = ((3 * 4 + quad) * 16 + col);

    // 4-deep feature prefetch ring (maxlen >= 256, no clamp needed at init)
    float fA0 = feats[fb0 + 1 * NLAB], fA1 = feats[fb1 + 1 * NLAB],
          fA2 = feats[fb2 + 1 * NLAB], fA3 = feats[fb3 + 1 * NLAB];
    float fB0 = feats[fb0 + 2 * NLAB], fB1 = feats[fb1 + 2 * NLAB],
          fB2 = feats[fb2 + 2 * NLAB], fB3 = feats[fb3 + 2 * NLAB];
    float fC0 = feats[fb0 + 3 * NLAB], fC1 = feats[fb1 + 3 * NLAB],
          fC2 = feats[fb2 + 3 * NLAB], fC3 = feats[fb3 + 3 * NLAB];
    float fD0 = feats[fb0 + 4 * NLAB], fD1 = feats[fb1 + 4 * NLAB],
          fD2 = feats[fb2 + 4 * NLAB], fD3 = feats[fb3 + 4 * NLAB];

    for (int t = 1; t < maxlen; ++t) {
        const bool lv0 = t < len0, lv1 = t < len1, lv2 = t < len2, lv3 = t < len3;
        const float p0 = __expf(u0 - n4.x);
        const float p1 = __expf(u1 - n4.y);
        const float p2 = __expf(u2 - n4.z);
        const float p3 = __expf(u3r - n4.w);
        if (lv0) C0 += n4.x;
        if (lv1) C1 += n4.y;
        if (lv2) C2 += n4.z;
        if (lv3) C3 += n4.w;

        const int buf = t & 1;
        unsigned short* Pb = P16[buf];
        Pb[wa0] = f2bf(p0);
        Pb[wa1] = f2bf(p1);
        Pb[wa2] = f2bf(p2);
        Pb[wa3] = f2bf(p3);

        const float ft0 = fA0, ft1 = fA1, ft2 = fA2, ft3 = fA3;
        fA0 = fB0; fA1 = fB1; fA2 = fB2; fA3 = fB3;
        fB0 = fC0; fB1 = fC1; fB2 = fC2; fB3 = fC3;
        fC0 = fD0; fC1 = fD1; fC2 = fD2; fC3 = fD3;
        int tp = t + 4; if (tp >= maxlen) tp = maxlen - 1;
        const int fo = tp * NLAB;
        fD0 = feats[fb0 + fo]; fD1 = feats[fb1 + fo];
        fD2 = feats[fb2 + fo]; fD3 = feats[fb3 + fo];

        __syncthreads();                               // the ONLY barrier/step
        const float4 nn4 = ((const float4*)u3_sh[(t - 1) & 1])[quad];

        const s16x8* PA = (const s16x8*)Pb;
        const s16x8 a0 = PA[ca0];
        const s16x8 a1 = PA[ca1];
        const s16x8 a2 = PA[ca2];
        const s16x8 a3 = PA[ca3];
        f32x4 acc = {0.f, 0.f, 0.f, 0.f};
        acc = __builtin_amdgcn_mfma_f32_16x16x32_bf16(a0, Bf0, acc, 0, 0, 0);
        acc = __builtin_amdgcn_mfma_f32_16x16x32_bf16(a1, Bf1, acc, 0, 0, 0);
        acc = __builtin_amdgcn_mfma_f32_16x16x32_bf16(a2, Bf2, acc, 0, 0, 0);
        acc = __builtin_amdgcn_mfma_f32_16x16x32_bf16(a3, Bf3, acc, 0, 0, 0);

        if (lv0) u0 = __logf(acc[0]) + ft0;
        if (lv1) u1 = __logf(acc[1]) + ft1;
        if (lv2) u2 = __logf(acc[2]) + ft2;
        if (lv3) u3r = __logf(acc[3]) + ft3;

        if (w == 0 && col == 3) {
            u3_sh[buf][quad * 4 + 0] = u0;
            u3_sh[buf][quad * 4 + 1] = u1;
            u3_sh[buf][quad * 4 + 2] = u2;
            u3_sh[buf][quad * 4 + 3] = u3r;
        }
        n4 = nn4;
    }

    // ---- logZ_b = C_b + logsumexp_j(u[b][j] + tr[j,EOS]) (exact) ----
    float v0 = u0 + C0 + trE;
    float v1 = u1 + C1 + trE;
    float v2 = u2 + C2 + trE;
    float v3 = u3r + C3 + trE;
    float m0 = v0, m1 = v1, m2 = v2, m3 = v3;
    #pragma unroll
    for (int off = 1; off < 16; off <<= 1) {
        m0 = fmaxf(m0, __shfl_xor(m0, off, 64));
        m1 = fmaxf(m1, __shfl_xor(m1, off, 64));
        m2 = fmaxf(m2, __shfl_xor(m2, off, 64));
        m3 = fmaxf(m3, __shfl_xor(m3, off, 64));
    }
    if (col == 0) {
        red_m[w][quad * 4 + 0] = m0;
        red_m[w][quad * 4 + 1] = m1;
        red_m[w][quad * 4 + 2] = m2;
        red_m[w][quad * 4 + 3] = m3;
    }
    __syncthreads();
    if (tid < MB) {
        float mm = red_m[0][tid];
        #pragma unroll
        for (int ww = 1; ww < 8; ++ww) mm = fmaxf(mm, red_m[ww][tid]);
        mfin[tid] = mm;
    }
    __syncthreads();
    const float4 M4 = ((const float4*)mfin)[quad];
    float e0 = __expf(v0 - M4.x);
    float e1 = __expf(v1 - M4.y);
    float e2 = __expf(v2 - M4.z);
    float e3 = __expf(v3 - M4.w);
    #pragma unroll
    for (int off = 1; off < 16; off <<= 1) {
        e0 += __shfl_xor(e0, off, 64);
        e1 += __shfl_xor(e1, off, 64);
        e2 += __shfl_xor(e2, off, 64);
        e3 += __shfl_xor(e3, off, 64);
    }
    if (col == 0) {
        red_s[w][quad * 4 + 0] = e0;
        red_s[w][quad * 4 + 1] = e1;
        red_s[w][quad * 4 + 2] = e2;
        red_s[w][quad * 4 + 3] = e3;
    }
    __syncthreads();
    if (tid < MB) {
        float ss = 0.f;
        #pragma unroll
        for (int ww = 0; ww < 8; ++ww) ss += red_s[ww][tid];
        logZ_out[blk * MB + tid] = mfin[tid] + __logf(ss);
    }
}

// ---- final reduction: out = mean(logZ - gold) ------------------------------
__global__ void crf_finalize(const float* __restrict__ gold,
                             const float* __restrict__ logZ,
                             float* __restrict__ out) {
    __shared__ float sh[4];
    const int i = threadIdx.x;  // 256 threads
    float v = (logZ[i] - gold[i]) + (logZ[i + 256] - gold[i + 256]);
    #pragma unroll
    for (int off = 32; off > 0; off >>= 1)
        v += __shfl_xor(v, off, 64);
    if ((i & 63) == 0) sh[i >> 6] = v;
    __syncthreads();
    if (i == 0) out[0] = (sh[0] + sh[1] + sh[2] + sh[3]) * (1.0f / (float)BB);
}

extern "C" void kernel_launch(void* const* d_in, const int* in_sizes, int n_in,
                              void* d_out, int out_size, void* d_ws, size_t ws_size,
                              hipStream_t stream) {
    const float*         feats = (const float*)d_in[0];
    const int*           tags  = (const int*)d_in[1];
    const unsigned char* m8    = (const unsigned char*)d_in[2];
    const float*         tr    = (const float*)d_in[3];

    float* gold = (float*)d_ws;       // 512 floats
    float* logZ = gold + BB;          // 512 floats
    float* out  = (float*)d_out;

    hipLaunchKernelGGL(crf_forward,  dim3(BB / MB), dim3(512), 0, stream,
                       feats, tags, m8, tr, gold, logZ);
    hipLaunchKernelGGL(crf_finalize, dim3(1), dim3(256), 0, stream,
                       gold, logZ, out);
}

// Round 6
// 474.521 us; speedup vs baseline: 1.1322x; 1.1322x over previous
//
#include <hip/hip_runtime.h>
#include <cstdint>
#include <cstddef>

#define NLAB 128
#define TT   512
#define BB   512
#define MB   16        // batches per block
#define PAD_ 0
#define BOS_ 1
#define EOS_ 2
#define LN2F 0.6931471805599453f

typedef float f32x4 __attribute__((ext_vector_type(4)));
typedef short s16x8 __attribute__((ext_vector_type(8)));

// ---- mask dtype hedge: bool(1B) vs int32(4B) -------------------------------
__device__ __forceinline__ bool mask_is_i32(const unsigned char* m8) {
    return m8[1] == 0;   // mask[0][1] always true; int32 high byte => 0
}
__device__ __forceinline__ bool mask_at(const unsigned char* m8, int idx, bool isi) {
    if (isi) return ((const int*)m8)[idx] != 0;
    return m8[idx] != 0;
}

__device__ __forceinline__ unsigned f2bf(float f) {
    union { float f; unsigned u; } v; v.f = f;
    return (v.u + 0x7FFFu + ((v.u >> 16) & 1u)) >> 16;   // RNE; inputs finite >= 0
}

// A-fragment of E^T for mfma: lane holds A[m][k]=E[k][m], m=w*16+col, k=kbase+jj
__device__ __forceinline__ s16x8 eafrag(const float* __restrict__ tr, int kbase, int m) {
    s16x8 r;
    #pragma unroll
    for (int jj = 0; jj < 8; ++jj)
        r[jj] = (short)f2bf(__expf(tr[(kbase + jj) * NLAB + m]));
    return r;
}

// ---- forward + gold fused: 16 batches / block, 512 thr (8 waves) -----------
// Linear-space recursion p_{t+1} = (p_t E) o exp(feat), MFMA-transposed
// (S^T = E^T P^T): lane owns 4 consecutive LABELS of ONE batch (batch = col).
// Lagged power-of-2 rescale via label-3 exponent broadcast; C += e*ln2.
__global__ __launch_bounds__(512, 2) void crf_forward(
        const float* __restrict__ feats,
        const int*   __restrict__ tags,
        const unsigned char* __restrict__ m8,
        const float* __restrict__ tr,
        float* __restrict__ gold_out,
        float* __restrict__ logZ_out) {
    const int tid  = threadIdx.x;
    const int blk  = blockIdx.x;
    const int w    = tid >> 6;       // wave 0..7 = out-label M-tile
    const int l    = tid & 63;
    const int quad = l >> 4;
    const int col  = l & 15;         // batch index within block
    const bool isi = mask_is_i32(m8);

    __shared__ __align__(16) unsigned short P16[2][2048];  // P^T bf16, B-frag layout
    __shared__ int   scale_sh[2][MB];
    __shared__ float n_sh[MB];
    __shared__ float gsh[MB];
    __shared__ int   csh[MB];
    __shared__ int   len_sh[MB];
    __shared__ float red_s[8][MB];

    // ---- gold + length: 32 threads per batch ----
    {
        const int bl = tid >> 5, sub = tid & 31;
        const int Bg = blk * MB + bl;
        const size_t fb = (size_t)Bg * TT * NLAB;
        float gp = 0.f; int cnt = 0;
        for (int tt = sub; tt < TT; tt += 32) {
            const int idx = Bg * TT + tt;
            const bool mm = mask_at(m8, idx, isi);
            cnt += mm ? 1 : 0;
            const int tg = tags[idx];
            if (tt == 0) gp += feats[fb + tg] + tr[BOS_ * NLAB + tg];
            else if (mm) gp += feats[fb + (size_t)tt * NLAB + tg]
                             + tr[tags[idx - 1] * NLAB + tg];
        }
        #pragma unroll
        for (int off = 16; off > 0; off >>= 1) {
            gp  += __shfl_xor(gp,  off, 64);
            cnt += __shfl_xor(cnt, off, 64);
        }
        if (sub == 0) { gsh[bl] = gp; csh[bl] = cnt; }
    }
    __syncthreads();
    if (tid < MB) {
        const int len = csh[tid];
        len_sh[tid] = len;
        const int Bg = blk * MB + tid;
        const int last = tags[Bg * TT + (len - 1)];
        gold_out[Bg] = gsh[tid] + tr[last * NLAB + EOS_];
        scale_sh[0][tid] = 0;
    }

    // ---- loop-invariant E^T A-fragments (16 VGPRs/lane) ----
    const int m_abs = w * 16 + col;
    const s16x8 Af0 = eafrag(tr, 0 * 32 + quad * 8, m_abs);
    const s16x8 Af1 = eafrag(tr, 1 * 32 + quad * 8, m_abs);
    const s16x8 Af2 = eafrag(tr, 2 * 32 + quad * 8, m_abs);
    const s16x8 Af3 = eafrag(tr, 3 * 32 + quad * 8, m_abs);

    const int mlab0 = w * 16 + quad * 4;    // lane's 4 labels: mlab0..mlab0+3
    const float trB0 = tr[BOS_ * NLAB + mlab0 + 0];
    const float trB1 = tr[BOS_ * NLAB + mlab0 + 1];
    const float trB2 = tr[BOS_ * NLAB + mlab0 + 2];
    const float trB3 = tr[BOS_ * NLAB + mlab0 + 3];
    const float trE0 = tr[(mlab0 + 0) * NLAB + EOS_];
    const float trE1 = tr[(mlab0 + 1) * NLAB + EOS_];
    const float trE2 = tr[(mlab0 + 2) * NLAB + EOS_];
    const float trE3 = tr[(mlab0 + 3) * NLAB + EOS_];

    const int Bg = blk * MB + col;
    const size_t fcol = (size_t)Bg * TT * NLAB + mlab0;   // float4-aligned

    const float4 f0 = *(const float4*)(feats + fcol);
    const float u0 = trB0 + f0.x, u1 = trB1 + f0.y,
                u2 = trB2 + f0.z, u3 = trB3 + f0.w;
    if (w == 0 && quad == 0) n_sh[col] = u3;   // label 3 always live
    __syncthreads();

    const int mylen = len_sh[col];
    int maxlen = 0;
    #pragma unroll
    for (int b = 0; b < MB; ++b) maxlen = max(maxlen, len_sh[b]);
    const float n0 = n_sh[col];

    float4 pf;                         // fp32 copy of lane's 4 p values
    pf.x = __expf(u0 - n0); pf.y = __expf(u1 - n0);
    pf.z = __expf(u2 - n0); pf.w = __expf(u3 - n0);
    float C = n0;                      // true log p = log pf + C

    // B-frag LDS address: addr16(k,n) = ((k>>3)*16+n)*8 + (k&7); lane's 4
    // labels are consecutive -> one b64 write, conflict-free.
    const int wbase = ((w * 2 + (quad >> 1)) * 16 + col) * 8 + (quad & 1) * 4;
    {
        const unsigned lo = f2bf(pf.x) | (f2bf(pf.y) << 16);
        const unsigned hi = f2bf(pf.z) | (f2bf(pf.w) << 16);
        *(uint2*)(&P16[0][wbase]) = make_uint2(lo, hi);
    }

#define LDF(tt) (*(const float4*)(feats + fcol + (size_t)(tt) * NLAB))
    // 8-step feature ring in NAMED registers (SROA-proof)
    float4 fA = LDF(min(1, maxlen - 1)), fB = LDF(min(2, maxlen - 1)),
           fC = LDF(min(3, maxlen - 1)), fD = LDF(min(4, maxlen - 1)),
           fE = LDF(min(5, maxlen - 1)), fF = LDF(min(6, maxlen - 1)),
           fG = LDF(min(7, maxlen - 1)), fH = LDF(min(8, maxlen - 1));

    const f32x4 zacc = {0.f, 0.f, 0.f, 0.f};
    const s16x8* PA0 = (const s16x8*)P16[0];
    const s16x8* PA1 = (const s16x8*)P16[1];
    const int ra0 = (0 * 4 + quad) * 16 + col;
    const int ra1 = (1 * 4 + quad) * 16 + col;
    const int ra2 = (2 * 4 + quad) * 16 + col;
    const int ra3 = (3 * 4 + quad) * 16 + col;

#define STEP(ii, FR) {                                                        \
        const int t = t0 + (ii);                                              \
        __syncthreads();                                                      \
        const int pb = (t - 1) & 1;                                           \
        const int e  = scale_sh[pb][col];                                     \
        const s16x8* PA = pb ? PA1 : PA0;                                     \
        const s16x8 b0 = PA[ra0], b1 = PA[ra1], b2 = PA[ra2], b3 = PA[ra3];   \
        f32x4 acc0 = __builtin_amdgcn_mfma_f32_16x16x32_bf16(Af0, b0, zacc, 0, 0, 0); \
        acc0 = __builtin_amdgcn_mfma_f32_16x16x32_bf16(Af1, b1, acc0, 0, 0, 0);       \
        f32x4 acc1 = __builtin_amdgcn_mfma_f32_16x16x32_bf16(Af2, b2, zacc, 0, 0, 0); \
        acc1 = __builtin_amdgcn_mfma_f32_16x16x32_bf16(Af3, b3, acc1, 0, 0, 0);       \
        const f32x4 acc = acc0 + acc1;                                        \
        const bool live = t < mylen;                                          \
        const float qx = ldexpf(acc[0] * __expf(FR.x), -e);                   \
        const float qy = ldexpf(acc[1] * __expf(FR.y), -e);                   \
        const float qz = ldexpf(acc[2] * __expf(FR.z), -e);                   \
        const float qw = ldexpf(acc[3] * __expf(FR.w), -e);                   \
        if (live) { pf.x = qx; pf.y = qy; pf.z = qz; pf.w = qw;               \
                    C += (float)e * LN2F; }                                   \
        const unsigned lo = f2bf(pf.x) | (f2bf(pf.y) << 16);                  \
        const unsigned hi = f2bf(pf.z) | (f2bf(pf.w) << 16);                  \
        *(uint2*)(&P16[t & 1][wbase]) = make_uint2(lo, hi);                   \
        if (w == 0 && quad == 0) {                                            \
            const int se = (int)((__float_as_uint(pf.w) >> 23) & 255u) - 126; \
            scale_sh[t & 1][col] = se;                                        \
        }                                                                     \
    }

    for (int t0 = 1; t0 < maxlen; t0 += 8) {
        const int nstep = min(8, maxlen - t0);
        if (nstep > 0) STEP(0, fA)
        if (nstep > 1) STEP(1, fB)
        if (nstep > 2) STEP(2, fC)
        if (nstep > 3) STEP(3, fD)
        if (nstep > 4) STEP(4, fE)
        if (nstep > 5) STEP(5, fF)
        if (nstep > 6) STEP(6, fG)
        if (nstep > 7) STEP(7, fH)
        if (t0 + 8 < maxlen) {      // burst refill: ONE vmcnt drain per 8 steps
            const int mx = maxlen - 1;
            fA = LDF(min(t0 + 8,  mx)); fB = LDF(min(t0 + 9,  mx));
            fC = LDF(min(t0 + 10, mx)); fD = LDF(min(t0 + 11, mx));
            fE = LDF(min(t0 + 12, mx)); fF = LDF(min(t0 + 13, mx));
            fG = LDF(min(t0 + 14, mx)); fH = LDF(min(t0 + 15, mx));
        }
    }
#undef STEP
#undef LDF

    // ---- logZ_b = C_b + log(sum_j p[j][b] * exp(tr[j,EOS])) ----
    float s = pf.x * __expf(trE0) + pf.y * __expf(trE1)
            + pf.z * __expf(trE2) + pf.w * __expf(trE3);
    s += __shfl_xor(s, 16, 64);
    s += __shfl_xor(s, 32, 64);
    if (l < 16) red_s[w][col] = s;
    __syncthreads();
    if (tid < MB) {
        float S = 0.f;
        #pragma unroll
        for (int ww = 0; ww < 8; ++ww) S += red_s[ww][tid];
        logZ_out[blk * MB + tid] = C + __logf(S);   // lane tid's C == batch tid's C
    }
}

// ---- final reduction: out = mean(logZ - gold) ------------------------------
__global__ void crf_finalize(const float* __restrict__ gold,
                             const float* __restrict__ logZ,
                             float* __restrict__ out) {
    __shared__ float sh[4];
    const int i = threadIdx.x;  // 256 threads
    float v = (logZ[i] - gold[i]) + (logZ[i + 256] - gold[i + 256]);
    #pragma unroll
    for (int off = 32; off > 0; off >>= 1)
        v += __shfl_xor(v, off, 64);
    if ((i & 63) == 0) sh[i >> 6] = v;
    __syncthreads();
    if (i == 0) out[0] = (sh[0] + sh[1] + sh[2] + sh[3]) * (1.0f / (float)BB);
}

extern "C" void kernel_launch(void* const* d_in, const int* in_sizes, int n_in,
                              void* d_out, int out_size, void* d_ws, size_t ws_size,
                              hipStream_t stream) {
    const float*         feats = (const float*)d_in[0];
    const int*           tags  = (const int*)d_in[1];
    const unsigned char* m8    = (const unsigned char*)d_in[2];
    const float*         tr    = (const float*)d_in[3];

    float* gold = (float*)d_ws;       // 512 floats
    float* logZ = gold + BB;          // 512 floats
    float* out  = (float*)d_out;

    hipLaunchKernelGGL(crf_forward,  dim3(BB / MB), dim3(512), 0, stream,
                       feats, tags, m8, tr, gold, logZ);
    hipLaunchKernelGGL(crf_finalize, dim3(1), dim3(256), 0, stream,
                       gold, logZ, out);
}